// Round 8
// baseline (4172.595 us; speedup 1.0000x reference)
//
#include <hip/hip_runtime.h>
#include <cfloat>

// Problem constants: B=4, N=M=8192, D=3, fp32. Points ~ N(0,1)^3.
#define NPTS   32768           // points per tensor (B*N)
#define G      32              // grid cells per axis
#define NCELL  (G*G*G)         // 32768 cells
#define NGRIDS 8               // (tensor 0/1) x (batch 0..3)
#define XMINF  (-5.0f)         // grid covers [-5,5]^3; outliers clamped (exactness preserved)
#define HCELL  0.3125f         // 10/32, exact in fp32
#define INVH   3.2f
#define NW     8               // target-slice waves per query chunk
#define NCH    128             // query chunks per grid (8192/64)

// Monotone float->uint map so uint atomicMin == float min.
__device__ __forceinline__ unsigned fmap(float f){ unsigned u=__float_as_uint(f); return (u&0x80000000u)?~u:(u|0x80000000u); }
__device__ __forceinline__ float funmap(unsigned u){ u=(u&0x80000000u)?(u&0x7FFFFFFFu):~u; return __uint_as_float(u); }

__device__ __forceinline__ int cell_coord(float x){
    int i = (int)floorf((x - XMINF) * INVH);
    return min(max(i, 0), G - 1);
}

__device__ __forceinline__ int wredmin(int v){
    #pragma unroll
    for (int m = 1; m < 64; m <<= 1) v = min(v, __shfl_xor(v, m, 64));
    return v;
}
__device__ __forceinline__ int wredmax(int v){
    #pragma unroll
    for (int m = 1; m < 64; m <<= 1) v = max(v, __shfl_xor(v, m, 64));
    return v;
}

// --- pass 1: per-cell histogram -------------------------------------------
__global__ void k_hist(const float* __restrict__ gts, const float* __restrict__ preds,
                       unsigned* __restrict__ counts){
    int tid = blockIdx.x * 256 + threadIdx.x;       // 0..65535
    int tensor = tid >> 15, k = tid & (NPTS - 1);
    const float* s = tensor ? preds : gts;
    float x = s[3*k], y = s[3*k+1], z = s[3*k+2];
    int b = k >> 13;
    int cc = (cell_coord(z)*G + cell_coord(y))*G + cell_coord(x);
    atomicAdd(&counts[(tensor*4 + b)*NCELL + cc], 1u);
}

// --- pass 2: per-grid exclusive scan (+ init mins, zero out) ---------------
__global__ void k_scan(const unsigned* __restrict__ counts, unsigned* __restrict__ offs,
                       unsigned* __restrict__ mins, float* __restrict__ out, int out_size){
    int g = blockIdx.x, t = threadIdx.x;            // 8 blocks x 1024
    const unsigned* c = counts + g*NCELL;
    unsigned* o = offs + g*NCELL;
    unsigned loc[32], s = 0;
    #pragma unroll
    for (int i = 0; i < 32; ++i){ loc[i] = s; s += c[t*32 + i]; }
    __shared__ unsigned ps[1024];
    ps[t] = s; __syncthreads();
    for (int d = 1; d < 1024; d <<= 1){
        unsigned v = (t >= d) ? ps[t - d] : 0u; __syncthreads();
        ps[t] += v; __syncthreads();
    }
    unsigned base = t ? ps[t-1] : 0u;
    #pragma unroll
    for (int i = 0; i < 32; ++i) o[t*32 + i] = base + loc[i];
    #pragma unroll
    for (int i = 0; i < 8; ++i) mins[g*8192 + t*8 + i] = 0xFFFFFFFFu;
    if (g == 0 && t < out_size) out[t] = 0.f;
}

// --- pass 3: scatter points into cell-sorted order (offs becomes END) ------
__global__ void k_scatter(const float* __restrict__ gts, const float* __restrict__ preds,
                          unsigned* __restrict__ offs, float4* __restrict__ sorted){
    int tid = blockIdx.x * 256 + threadIdx.x;
    int tensor = tid >> 15, k = tid & (NPTS - 1);
    const float* s = tensor ? preds : gts;
    float x = s[3*k], y = s[3*k+1], z = s[3*k+2];
    int b = k >> 13;
    int gid = tensor*4 + b;
    int cc = (cell_coord(z)*G + cell_coord(y))*G + cell_coord(x);
    unsigned slot = atomicAdd(&offs[gid*NCELL + cc], 1u);
    sorted[gid*8192 + slot] = make_float4(x, y, z, 0.5f*(x*x + y*y + z*z));
}

// Process one target cell's slice-w (every NW-th element), 2-wide for ILP.
__device__ __forceinline__ void visit_cell(int cc, const unsigned* __restrict__ tco,
                                           const unsigned* __restrict__ tof,
                                           const float4* __restrict__ TS,
                                           int w, float4 q, float& m){
    unsigned n = tco[cc]; if (!n) return;
    unsigned e = tof[cc];                    // END after scatter bump
    unsigned j = e - n + (unsigned)w;
    while (j + NW < e){
        float4 a = TS[j], c = TS[j + NW];
        float sa = fmaf(-q.x, a.x, fmaf(-q.y, a.y, fmaf(-q.z, a.z, a.w)));
        float sc = fmaf(-q.x, c.x, fmaf(-q.y, c.y, fmaf(-q.z, c.z, c.w)));
        m = fminf(m, sa); m = fminf(m, sc);
        j += 2*NW;
    }
    if (j < e){
        float4 a = TS[j];
        m = fminf(m, fmaf(-q.x, a.x, fmaf(-q.y, a.y, fmaf(-q.z, a.z, a.w))));
    }
}

// --- pass 4: exact NN via expanding shells around each wave's query box ----
// Block = 1 wave = 64 consecutive cell-sorted queries (full lane occupancy,
// compact bounding box). NW=8 blocks per chunk slice the target lists 8 ways
// (TLP; per-slice stop bound is conservative -> exact per slice; atomicMin
// merges). Termination: shell r+1 lower bound (gap - eps, floored at 0)
// squared > per-lane best dist^2 for ALL lanes, or grid covered.
__global__ void __launch_bounds__(64) k_search(const unsigned* __restrict__ counts,
        const unsigned* __restrict__ offs, const float4* __restrict__ sorted,
        unsigned* __restrict__ mins){
    int bid = blockIdx.x;                    // 8192
    int w   = bid & (NW - 1);
    int c   = bid >> 3;                      // 1024 chunks
    int gq  = c >> 7, ch = c & (NCH - 1);
    int dir = gq >> 2, b = gq & 3;
    int qgrid = dir*4 + b, tgrid = (dir ^ 1)*4 + b;
    int lane = threadIdx.x;

    const float4* QS = sorted + qgrid*8192;
    const float4* TS = sorted + tgrid*8192;
    const unsigned* tco = counts + tgrid*NCELL;
    const unsigned* tof = offs + tgrid*NCELL;

    int qi = ch*64 + lane;
    float4 q = QS[qi];                       // coalesced; every query covered once

    int hx = cell_coord(q.x), hy = cell_coord(q.y), hz = cell_coord(q.z);
    int bxlo = wredmin(hx), bxhi = wredmax(hx);
    int bylo = wredmin(hy), byhi = wredmax(hy);
    int bzlo = wredmin(hz), bzhi = wredmax(hz);

    float m = FLT_MAX;                       // min over slice of (||t||^2/2 - q.t)

    for (int r = 0; ; ++r){
        if (r == 0){
            for (int cz = bzlo; cz <= bzhi; ++cz)
                for (int cy = bylo; cy <= byhi; ++cy)
                    for (int cx = bxlo; cx <= bxhi; ++cx)
                        visit_cell((cz*G + cy)*G + cx, tco, tof, TS, w, q, m);
        } else {
            for (int cz = bzlo - r; cz <= bzhi + r; ++cz){
                if ((unsigned)cz >= (unsigned)G) continue;
                int ez = (cz == bzlo - r) | (cz == bzhi + r);
                for (int cy = bylo - r; cy <= byhi + r; ++cy){
                    if ((unsigned)cy >= (unsigned)G) continue;
                    int exy = ez | (cy == bylo - r) | (cy == byhi + r);
                    int xs = bxlo - r, xe = bxhi + r;
                    int step = exy ? 1 : (xe - xs);      // >= 2 when r >= 1
                    for (int cx = xs; cx <= xe; cx += step)
                        if ((unsigned)cx < (unsigned)G)
                            visit_cell((cz*G + cy)*G + cx, tco, tof, TS, w, q, m);
                }
            }
        }
        bool covered = (bxlo - r <= 0) & (bxhi + r >= G-1) & (bylo - r <= 0) &
                       (byhi + r >= G-1) & (bzlo - r <= 0) & (bzhi + r >= G-1);
        if (covered) break;                  // all cells visited: exact
        float best2 = 2.f*(m + q.w);         // +inf while slice empty -> keep going
        float gxp = (bxhi + 1 + r)*HCELL + XMINF - q.x;
        float gxm = q.x - ((bxlo - r)*HCELL + XMINF);
        float gyp = (byhi + 1 + r)*HCELL + XMINF - q.y;
        float gym = q.y - ((bylo - r)*HCELL + XMINF);
        float gzp = (bzhi + 1 + r)*HCELL + XMINF - q.z;
        float gzm = q.z - ((bzlo - r)*HCELL + XMINF);
        float gg = fminf(fminf(fminf(gxp, gxm), fminf(gyp, gym)), fminf(gzp, gzm));
        gg = fmaxf(gg - 1e-4f, 0.f);         // eps guards fp binning error; max(0)
                                             // guards clamped out-of-grid queries
        if (__all(gg*gg > best2)) break;
    }
    atomicMin(&mins[qgrid*8192 + ch*64 + lane], fmap(m));
}

// --- pass 5: sum 2*(min + ||q||^2/2) over all 65536 queries ----------------
__global__ void k_finish(const unsigned* __restrict__ mins,
                         const float4* __restrict__ sorted, float* __restrict__ out){
    int tid = blockIdx.x*256 + threadIdx.x;  // 65536; index-aligned with sorted
    float val = 2.f*(funmap(mins[tid]) + sorted[tid].w);
    #pragma unroll
    for (int off = 32; off; off >>= 1) val += __shfl_down(val, off, 64);
    __shared__ float sred[4];
    int lane = threadIdx.x & 63, wv = threadIdx.x >> 6;
    if (!lane) sred[wv] = val;
    __syncthreads();
    if (!threadIdx.x) atomicAdd(out, sred[0] + sred[1] + sred[2] + sred[3]);
}

extern "C" void kernel_launch(void* const* d_in, const int* in_sizes, int n_in,
                              void* d_out, int out_size, void* d_ws, size_t ws_size,
                              hipStream_t stream) {
    const float* gts   = (const float*)d_in[0];
    const float* preds = (const float*)d_in[1];
    float* out = (float*)d_out;

    char* ws = (char*)d_ws;                  // 3.25 MB used
    unsigned* counts = (unsigned*)(ws);                 // 1 MB
    unsigned* offs   = (unsigned*)(ws + (1u << 20));    // 1 MB (becomes END)
    float4*   sorted = (float4*)  (ws + (2u << 20));    // 1 MB
    unsigned* mins   = (unsigned*)(ws + (3u << 20));    // 256 KB

    hipMemsetAsync(counts, 0, (size_t)NGRIDS * NCELL * 4, stream);
    k_hist   <<<256, 256, 0, stream>>>(gts, preds, counts);
    k_scan   <<<8, 1024, 0, stream>>>(counts, offs, mins, out, out_size);
    k_scatter<<<256, 256, 0, stream>>>(gts, preds, offs, sorted);
    k_search <<<NGRIDS * NCH * NW, 64, 0, stream>>>(counts, offs, sorted, mins);
    k_finish <<<256, 256, 0, stream>>>(mins, sorted, out);
}

// Round 10
// 119.716 us; speedup vs baseline: 34.8541x; 34.8541x over previous
//
#include <hip/hip_runtime.h>
#include <cfloat>

// Problem constants: B=4, N=M=8192, D=3, fp32. Points ~ N(0,1)^3.
#define NPTS   32768           // points per tensor
#define NB     512             // x-buckets per grid
#define NGRIDS 8               // (tensor 0/1) x (batch 0..3)
#define XMINF  (-5.0f)
#define HB     0.01953125f     // 10/512, exact in fp32
#define INVHB  51.2f
#define WXF    0.30f           // fixed half-window in x
#define GQ     512             // queries per group (64 lanes x QT)
#define QT     8               // queries per thread (proven VALU-bound ratio)
#define SEG    16              // window slices (blocks) per group
#define NGROUP 128             // 65536 / 512

__device__ __forceinline__ unsigned fmap(float f){ unsigned u=__float_as_uint(f); return (u&0x80000000u)?~u:(u|0x80000000u); }
__device__ __forceinline__ float funmap(unsigned u){ u=(u&0x80000000u)?(u&0x7FFFFFFFu):~u; return __uint_as_float(u); }
__device__ __forceinline__ int bucketi(float x){
    int i = (int)floorf((x - XMINF) * INVHB);
    return min(max(i, 0), NB - 1);
}

// --- pass 1: per-(grid,bucket) histogram of x ------------------------------
__global__ void k_hist(const float* __restrict__ gts, const float* __restrict__ preds,
                       unsigned* __restrict__ counts){
    int tid = blockIdx.x * 256 + threadIdx.x;      // 0..65535
    int tensor = tid >> 15, k = tid & (NPTS - 1);
    const float* s = tensor ? preds : gts;
    float x = s[3*k];
    int g = tensor*4 + (k >> 13);
    atomicAdd(&counts[g*NB + bucketi(x)], 1u);
}

// --- pass 2: per-grid exclusive scan; init mins; zero out ------------------
__global__ void k_scan(const unsigned* __restrict__ counts, unsigned* __restrict__ offs,
                       unsigned* __restrict__ mins, float* __restrict__ out, int out_size){
    int g = blockIdx.x, t = threadIdx.x;           // 8 blocks x 512
    unsigned c = counts[g*NB + t];
    __shared__ unsigned ps[NB];
    ps[t] = c; __syncthreads();
    for (int d = 1; d < NB; d <<= 1){
        unsigned v = ps[t], u = (t >= d) ? ps[t - d] : 0u;
        __syncthreads(); ps[t] = v + u; __syncthreads();
    }
    offs[g*NB + t] = ps[t] - c;                    // exclusive start
    #pragma unroll
    for (int i = 0; i < 16; ++i) mins[g*8192 + t*16 + i] = 0xFFFFFFFFu;
    if (g == 0 && t < out_size) out[t] = 0.f;
}

// --- pass 3: scatter (x,y,z,||p||^2/2) into x-sorted order (offs -> END) ---
__global__ void k_scatter(const float* __restrict__ gts, const float* __restrict__ preds,
                          unsigned* __restrict__ offs, float4* __restrict__ sorted){
    int tid = blockIdx.x * 256 + threadIdx.x;
    int tensor = tid >> 15, k = tid & (NPTS - 1);
    const float* s = tensor ? preds : gts;
    float x = s[3*k], y = s[3*k+1], z = s[3*k+2];
    int g = tensor*4 + (k >> 13);
    unsigned slot = atomicAdd(&offs[g*NB + bucketi(x)], 1u);
    sorted[g*8192 + slot] = make_float4(x, y, z, 0.5f*(x*x + y*y + z*z));
}

// --- pass 4: windowed brute + certificate + fused reduce -------------------
// Block = 1 wave; group = 512 consecutive x-sorted queries; window = targets
// in [gx_lo-WX, gx_hi+WX] (contiguous index range via bucket offs), split
// contiguously across SEG=16 slice-blocks. Inner loop = round-7's proven
// LDS-broadcast QT=8 stream (VALU-bound). Merge = atomicMin; last slice
// (ticket, vmcnt+barrier — NO threadfence, round-3 lesson) certifies each
// query: best <= margin-to-unscanned-bucket-edge => exact, sum it; else
// enqueue for the exact fallback pass.
__global__ void __launch_bounds__(64) k_main(const unsigned* __restrict__ offs,
        const float4* __restrict__ sorted, unsigned* __restrict__ mins,
        unsigned* __restrict__ tickets, unsigned* __restrict__ fbcnt,
        unsigned* __restrict__ fbq, float* __restrict__ out){
    __shared__ float4 st[64];
    __shared__ unsigned done;

    int bid = blockIdx.x;                 // 2048
    int w   = bid & (SEG - 1);
    int g   = bid >> 4;                   // group 0..127
    int qg  = g >> 4;                     // query grid 0..7
    int tg  = ((qg >> 2) ^ 1)*4 + (qg & 3);
    int lane = threadIdx.x;

    const float4* __restrict__ QS = sorted + qg*8192;
    const float4* __restrict__ TS = sorted + tg*8192;
    const unsigned* __restrict__ tof = offs + tg*NB;
    int q0 = (g & 15)*GQ + lane;          // local query base within qgrid

    float qx[QT], qy[QT], qz[QT], m[QT];
    float xlo = FLT_MAX, xhi = -FLT_MAX;
    #pragma unroll
    for (int k = 0; k < QT; ++k){
        float4 q = QS[q0 + 64*k];
        qx[k] = q.x; qy[k] = q.y; qz[k] = q.z; m[k] = FLT_MAX;
        xlo = fminf(xlo, q.x); xhi = fmaxf(xhi, q.x);
    }
    #pragma unroll
    for (int s = 1; s < 64; s <<= 1){
        xlo = fminf(xlo, __shfl_xor(xlo, s, 64));
        xhi = fmaxf(xhi, __shfl_xor(xhi, s, 64));
    }
    int blo = bucketi(xlo - WXF), bhi = bucketi(xhi + WXF);
    unsigned S = blo ? tof[blo - 1] : 0u; // offs are ENDS after scatter
    unsigned E = tof[bhi];
    unsigned len = E - S;
    unsigned s0 = S + (len * (unsigned)w) / SEG;
    unsigned e0 = S + (len * (unsigned)(w + 1)) / SEG;

    for (unsigned base = s0; base < e0; base += 64){
        unsigned idx = base + lane;
        if (idx < e0) st[lane] = TS[idx];            // global->reg->ds_write
        int cnt = (int)min(64u, e0 - base);          // wave-uniform
        for (int j = 0; j < cnt; ++j){
            float4 t = st[j];                        // broadcast ds_read_b128
            #pragma unroll
            for (int k = 0; k < QT; ++k){
                float s = fmaf(-qx[k], t.x, fmaf(-qy[k], t.y, fmaf(-qz[k], t.z, t.w)));
                m[k] = fminf(m[k], s);
            }
        }
    }

    #pragma unroll
    for (int k = 0; k < QT; ++k)
        atomicMin(&mins[qg*8192 + q0 + 64*k], fmap(m[k]));

    asm volatile("s_waitcnt vmcnt(0)" ::: "memory");
    __syncthreads();
    if (lane == 0) done = atomicAdd(&tickets[g], 1u);
    __syncthreads();
    if (done != SEG - 1) return;

    // winner: certificate + enqueue + partial sum
    float val = 0.f;
    #pragma unroll
    for (int k = 0; k < QT; ++k){
        unsigned u = atomicMin(&mins[qg*8192 + q0 + 64*k], 0xFFFFFFFFu); // coherent read
        float4 q = QS[q0 + 64*k];                    // L2-hot reload
        float b2 = 2.f*(funmap(u) + q.w);            // best dist^2 (>=0), inf if empty
        float ml = (blo > 0)      ? (q.x - (XMINF + blo*HB))       : FLT_MAX;
        float mr = (bhi < NB - 1) ? ((XMINF + (bhi + 1)*HB) - q.x) : FLT_MAX;
        float mg = fminf(ml, mr) - 1e-5f;            // eps: binning fp slack
        bool exact = (mg > 0.f) && (b2 <= mg*mg);
        if (exact) val += b2;
        else       fbq[atomicAdd(fbcnt, 1u)] = (unsigned)(qg*8192 + q0 + 64*k);
    }
    #pragma unroll
    for (int off = 32; off; off >>= 1) val += __shfl_down(val, off, 64);
    if (lane == 0) atomicAdd(out, val);
}

// --- pass 5: exact fallback. One wave per flagged query; one-shot range
// |dx| <= best_A (superset of where the true NN can live => exact). --------
__global__ void k_fallback(const unsigned* __restrict__ fbcnt,
                           const unsigned* __restrict__ fbq,
                           const unsigned* __restrict__ offs,
                           const float4* __restrict__ sorted,
                           const unsigned* __restrict__ mins,
                           float* __restrict__ out){
    unsigned n = *fbcnt;
    int wid  = (blockIdx.x * 256 + threadIdx.x) >> 6;
    int lane = threadIdx.x & 63;
    int nw   = (gridDim.x * 256) >> 6;
    for (unsigned i = (unsigned)wid; i < n; i += (unsigned)nw){
        unsigned qid = fbq[i];
        int qg = qid >> 13;
        int tg = ((qg >> 2) ^ 1)*4 + (qg & 3);
        const float4* TS = sorted + tg*8192;
        const unsigned* tof = offs + tg*NB;
        float4 q = sorted[qid];
        // pass-A best (merged via atomics in previous kernel; plain load OK
        // across kernel boundary on same stream)
        float b2 = 2.f*(funmap(mins[qid]) + q.w);
        float best = sqrtf(fmaxf(b2, 0.f));
        int blo = bucketi(q.x - best), bhi = bucketi(q.x + best);
        unsigned S = blo ? tof[blo - 1] : 0u;
        unsigned E = tof[bhi];
        float m = FLT_MAX;
        for (unsigned j = S + (unsigned)lane; j < E; j += 64u){
            float4 t = TS[j];
            m = fminf(m, fmaf(-q.x, t.x, fmaf(-q.y, t.y, fmaf(-q.z, t.z, t.w))));
        }
        #pragma unroll
        for (int s = 32; s; s >>= 1) m = fminf(m, __shfl_xor(m, s, 64));
        if (lane == 0) atomicAdd(out, 2.f*(m + q.w));
    }
}

extern "C" void kernel_launch(void* const* d_in, const int* in_sizes, int n_in,
                              void* d_out, int out_size, void* d_ws, size_t ws_size,
                              hipStream_t stream) {
    const float* gts   = (const float*)d_in[0];
    const float* preds = (const float*)d_in[1];
    float* out = (float*)d_out;

    char* ws = (char*)d_ws;
    unsigned* counts  = (unsigned*)(ws);                        // 16 KB
    unsigned* tickets = (unsigned*)(ws + 16384);                // 512 B
    unsigned* fbcnt   = (unsigned*)(ws + 16896);                // 4 B
    unsigned* offs    = (unsigned*)(ws + 20480);                // 16 KB
    float4*   sorted  = (float4*)  (ws + 65536);                // 1 MB
    unsigned* mins    = (unsigned*)(ws + 65536 + (size_t)NGRIDS*8192*16); // 256 KB
    unsigned* fbq     = (unsigned*)((char*)mins + (size_t)2*NPTS*4);      // 256 KB

    (void)hipMemsetAsync(ws, 0, 16900, stream); // counts + tickets + fbcnt
    k_hist    <<<256, 256, 0, stream>>>(gts, preds, counts);
    k_scan    <<<NGRIDS, NB, 0, stream>>>(counts, offs, mins, out, out_size);
    k_scatter <<<256, 256, 0, stream>>>(gts, preds, offs, sorted);
    k_main    <<<NGROUP*SEG, 64, 0, stream>>>(offs, sorted, mins, tickets, fbcnt, fbq, out);
    k_fallback<<<256, 256, 0, stream>>>(fbcnt, fbq, offs, sorted, mins, out);
}

// Round 11
// 98.287 us; speedup vs baseline: 42.4532x; 1.2180x over previous
//
#include <hip/hip_runtime.h>
#include <cfloat>

// Problem constants: B=4, N=M=8192, D=3, fp32. Points ~ N(0,1)^3.
#define NPTS   32768           // points per tensor
#define NB     512             // x-buckets per grid
#define NGRIDS 8               // (tensor 0/1) x (batch 0..3)
#define XMINF  (-5.0f)
#define HB     0.01953125f     // 10/512, exact in fp32
#define INVHB  51.2f
#define WXF    0.40f           // half-window in x (0.40: flagged ~5x rarer than 0.30)
#define GQ     512             // queries per group (64 lanes x QT)
#define QT     8               // queries per thread
#define SEG    16              // window slices per group
#define NGRP   128             // total groups (65536/512)

__device__ __forceinline__ unsigned fmap(float f){ unsigned u=__float_as_uint(f); return (u&0x80000000u)?~u:(u|0x80000000u); }
__device__ __forceinline__ float funmap(unsigned u){ u=(u&0x80000000u)?(u&0x7FFFFFFFu):~u; return __uint_as_float(u); }
__device__ __forceinline__ int bucketi(float x){
    int i = (int)floorf((x - XMINF) * INVHB);
    return min(max(i, 0), NB - 1);
}

// --- pass 1: per-grid histogram + scan + scatter + all init (ONE kernel) ---
// One block per (tensor,batch) grid: 1024 threads x 8 points each.
__global__ void __launch_bounds__(1024) k_prep(
        const float* __restrict__ gts, const float* __restrict__ preds,
        unsigned* __restrict__ offs, float4* __restrict__ sorted,
        unsigned* __restrict__ mins, unsigned* __restrict__ tickets,
        float* __restrict__ out, int out_size){
    __shared__ unsigned hist[NB];   // counts -> cursor
    __shared__ unsigned scn[NB];
    int g = blockIdx.x, t = threadIdx.x;
    int tensor = g >> 2, b = g & 3;
    const float* base = (tensor ? preds : gts) + (size_t)b * 8192 * 3;

    if (t < NB) hist[t] = 0u;
    __syncthreads();

    float px[8], py[8], pz[8]; int pb[8];
    #pragma unroll
    for (int i = 0; i < 8; ++i){
        int k = i * 1024 + t;
        px[i] = base[3*k]; py[i] = base[3*k+1]; pz[i] = base[3*k+2];
        pb[i] = bucketi(px[i]);
        atomicAdd(&hist[pb[i]], 1u);
    }
    __syncthreads();

    if (t < NB) scn[t] = hist[t];
    __syncthreads();
    for (int d = 1; d < NB; d <<= 1){
        unsigned v = 0u;
        if (t < NB && t >= d) v = scn[t - d];
        __syncthreads();
        if (t < NB) scn[t] += v;
        __syncthreads();
    }
    if (t < NB){
        offs[g*NB + t] = scn[t];            // bucket END (inclusive scan)
        hist[t] = scn[t] - hist[t];         // bucket START -> scatter cursor
    }
    __syncthreads();

    float4* dst = sorted + (size_t)g * 8192;
    #pragma unroll
    for (int i = 0; i < 8; ++i){
        unsigned slot = atomicAdd(&hist[pb[i]], 1u);
        dst[slot] = make_float4(px[i], py[i], pz[i],
                                0.5f*(px[i]*px[i] + py[i]*py[i] + pz[i]*pz[i]));
    }
    #pragma unroll
    for (int i = 0; i < 8; ++i) mins[g*8192 + i*1024 + t] = 0xFFFFFFFFu;
    if (g == 0){
        if (t < NGRP) tickets[t] = 0u;
        if (t < out_size) out[t] = 0.f;
    }
}

// --- pass 2: windowed brute + certificate + inline fallback + reduce -------
// 512 blocks x 256: group g2 = bid>>2 (512 x-sorted queries), slice w =
// (bid&3)*4 + wave (SEG=16 contiguous window slices). Inner loop = proven
// QT=8 LDS-broadcast stream, software-pipelined staging. Merge = atomicMin;
// ticket winner block (done==3; vmcnt+barrier ordering, NO threadfence —
// round-3 lesson) certifies each query (best <= margin-to-unscanned-bucket
// => exact), sums certified, and rescans flagged queries with all 4 waves
// over the one-shot exact range |dx| <= best_passA.
__global__ void __launch_bounds__(256, 4) k_main(
        const unsigned* __restrict__ offs, const float4* __restrict__ sorted,
        unsigned* __restrict__ mins, unsigned* __restrict__ tickets,
        float* __restrict__ out){
    __shared__ float4 st[4][64];
    __shared__ unsigned done, fcnt;
    __shared__ unsigned fqid[GQ];
    __shared__ float    fb2v[GQ];

    int bid = blockIdx.x;                 // 512
    int g2  = bid >> 2;                   // group 0..127
    int wv  = threadIdx.x >> 6, lane = threadIdx.x & 63;
    int w   = (bid & 3) * 4 + wv;         // slice 0..15
    int qg  = g2 >> 4;                    // query grid 0..7
    int tg  = ((qg >> 2) ^ 1) * 4 + (qg & 3);

    const float4* __restrict__ QS = sorted + (size_t)qg * 8192;
    const float4* __restrict__ TS = sorted + (size_t)tg * 8192;
    const unsigned* __restrict__ tof = offs + tg * NB;
    int q0 = (g2 & 15) * GQ + lane;       // same 512 queries for all 4 waves

    float qx[QT], qy[QT], qz[QT], m[QT];
    float xlo = FLT_MAX, xhi = -FLT_MAX;
    #pragma unroll
    for (int k = 0; k < QT; ++k){
        float4 q = QS[q0 + 64*k];
        qx[k] = q.x; qy[k] = q.y; qz[k] = q.z; m[k] = FLT_MAX;
        xlo = fminf(xlo, q.x); xhi = fmaxf(xhi, q.x);
    }
    #pragma unroll
    for (int s = 1; s < 64; s <<= 1){
        xlo = fminf(xlo, __shfl_xor(xlo, s, 64));
        xhi = fmaxf(xhi, __shfl_xor(xhi, s, 64));
    }
    int blo = bucketi(xlo - WXF), bhi = bucketi(xhi + WXF);
    unsigned S = blo ? tof[blo - 1] : 0u;   // offs are inclusive ENDS
    unsigned E = tof[bhi];
    unsigned len = E - S;
    unsigned s0 = S + (len * (unsigned)w) / SEG;
    unsigned e0 = S + (len * (unsigned)(w + 1)) / SEG;

    // software-pipelined: load next chunk while computing current (T14-lite)
    float4 cur = make_float4(0.f, 0.f, 0.f, 0.f);
    if (s0 + lane < e0) cur = TS[s0 + lane];
    for (unsigned bs = s0; bs < e0; bs += 64){
        st[wv][lane] = cur;
        unsigned ni = bs + 64 + lane;
        if (ni < e0) cur = TS[ni];
        int cnt = (int)min(64u, e0 - bs);
        for (int j = 0; j < cnt; ++j){
            float4 t = st[wv][j];            // broadcast ds_read_b128
            #pragma unroll
            for (int k = 0; k < QT; ++k){
                float s = fmaf(-qx[k], t.x, fmaf(-qy[k], t.y, fmaf(-qz[k], t.z, t.w)));
                m[k] = fminf(m[k], s);
            }
        }
    }

    #pragma unroll
    for (int k = 0; k < QT; ++k)
        atomicMin(&mins[qg*8192 + q0 + 64*k], fmap(m[k]));

    asm volatile("s_waitcnt vmcnt(0)" ::: "memory");  // my atomics complete
    __syncthreads();                                  // ... for ALL waves
    if (threadIdx.x == 0){ done = atomicAdd(&tickets[g2], 1u); fcnt = 0u; }
    __syncthreads();
    if (done != 3u) return;

    // winner block: wave 0 certifies + sums certified; flagged -> LDS list
    if (wv == 0){
        float val = 0.f;
        #pragma unroll
        for (int k = 0; k < QT; ++k){
            unsigned gi = (unsigned)(qg*8192 + q0 + 64*k);
            unsigned u = atomicMin(&mins[gi], 0xFFFFFFFFu);  // coherent read
            float4 q = QS[q0 + 64*k];
            float b2 = 2.f*(funmap(u) + q.w);                // best dist^2
            float ml = (blo > 0)      ? (q.x - (XMINF + blo*HB))       : FLT_MAX;
            float mr = (bhi < NB - 1) ? ((XMINF + (bhi + 1)*HB) - q.x) : FLT_MAX;
            float mg = fminf(ml, mr) - 1e-5f;                // fp binning slack
            if ((mg > 0.f) && (b2 <= mg*mg)) val += b2;
            else { unsigned p = atomicAdd(&fcnt, 1u); fqid[p] = gi; fb2v[p] = b2; }
        }
        #pragma unroll
        for (int off = 32; off; off >>= 1) val += __shfl_down(val, off, 64);
        if (lane == 0) atomicAdd(out, val);
    }
    __syncthreads();                       // list + fcnt visible to all waves

    // all 4 waves process flagged queries round-robin; exact one-shot range
    unsigned n = fcnt;
    for (unsigned i = (unsigned)wv; i < n; i += 4u){
        unsigned qid = fqid[i];
        float b2p = fb2v[i];
        float4 q = sorted[qid];            // qid is a global sorted index
        int b1, b2i;
        if (b2p < 3.0e38f){                // finite pass-A best
            float best = sqrtf(fmaxf(b2p, 0.f));
            b1 = bucketi(q.x - best); b2i = bucketi(q.x + best);
        } else { b1 = 0; b2i = NB - 1; }   // empty window: full scan
        unsigned S2 = b1 ? tof[b1 - 1] : 0u;
        unsigned E2 = tof[b2i];
        float mm = FLT_MAX;
        unsigned j = S2 + (unsigned)lane;
        for (; j + 64u < E2; j += 128u){
            float4 a = TS[j], c = TS[j + 64u];
            mm = fminf(mm, fmaf(-q.x, a.x, fmaf(-q.y, a.y, fmaf(-q.z, a.z, a.w))));
            mm = fminf(mm, fmaf(-q.x, c.x, fmaf(-q.y, c.y, fmaf(-q.z, c.z, c.w))));
        }
        if (j < E2){
            float4 a = TS[j];
            mm = fminf(mm, fmaf(-q.x, a.x, fmaf(-q.y, a.y, fmaf(-q.z, a.z, a.w))));
        }
        #pragma unroll
        for (int s = 32; s; s >>= 1) mm = fminf(mm, __shfl_xor(mm, s, 64));
        if (lane == 0) atomicAdd(out, 2.f*(mm + q.w));
    }
}

extern "C" void kernel_launch(void* const* d_in, const int* in_sizes, int n_in,
                              void* d_out, int out_size, void* d_ws, size_t ws_size,
                              hipStream_t stream) {
    const float* gts   = (const float*)d_in[0];
    const float* preds = (const float*)d_in[1];
    float* out = (float*)d_out;

    char* ws = (char*)d_ws;
    unsigned* offs    = (unsigned*)(ws);                        // 16 KB
    unsigned* tickets = (unsigned*)(ws + 16384);                // 512 B
    float4*   sorted  = (float4*)  (ws + 65536);                // 1 MB
    unsigned* mins    = (unsigned*)(ws + 65536 + (size_t)NGRIDS*8192*16); // 256 KB

    k_prep<<<NGRIDS, 1024, 0, stream>>>(gts, preds, offs, sorted, mins,
                                        tickets, out, out_size);
    k_main<<<NGRP * 4, 256, 0, stream>>>(offs, sorted, mins, tickets, out);
}